// Round 1
// baseline (655.894 us; speedup 1.0000x reference)
//
#include <hip/hip_runtime.h>
#include <math.h>

// Problem constants
#define BBATCH 8
#define CC 96
#define HH 224
#define NHW 32            // 224/7 windows per side
#define NWIN 1024
#define TOPK 256
#define PERK 24
#define DST 16
#define DTR 6
#define LL 12544          // 256*49
#define LC 98             // chunk length (2 windows)
#define TCH 128           // chunks: 128*98 = 12544
#define NBK 32            // B*4 directions

// workspace offsets (floats)
#define OFF_POOL 0
#define OFF_LOG  786432
#define OFF_PROB 794624
#define OFF_RW   802816
#define OFF_RANK 804864
#define OFF_SEL  813056
#define OFF_CP   815104
#define OFF_CS   2387968
#define OFF_HIN  3960832
// total 5,533,696 floats = 22.1 MB

// -------- K1: window pooling: pooledT[b][c][w] --------
__global__ void k_pool(const float* __restrict__ x, float* __restrict__ pooled) {
    int bc = blockIdx.x;                 // b*96+c
    const float* xp = x + (size_t)bc * HH * HH;
    float* pp = pooled + (size_t)bc * NWIN;
    for (int w = threadIdx.x; w < NWIN; w += blockDim.x) {
        int wr = w >> 5, wc = w & 31;
        const float* base = xp + (wr * 7) * HH + wc * 7;
        float s = 0.f;
        #pragma unroll
        for (int i = 0; i < 7; ++i) {
            #pragma unroll
            for (int j = 0; j < 7; ++j) s += base[i * HH + j];
        }
        pp[w] = s * (1.0f / 49.0f);
    }
}

// -------- K2: router MLP -> logits --------
__global__ void k_router(const float* __restrict__ pooled,
                         const float* __restrict__ w1, const float* __restrict__ b1,
                         const float* __restrict__ w2, const float* __restrict__ b2,
                         float* __restrict__ logits) {
    __shared__ float sw1[PERK * CC];
    __shared__ float sb1[PERK];
    __shared__ float sw2[PERK];
    for (int i = threadIdx.x; i < PERK * CC; i += blockDim.x) sw1[i] = w1[i];
    if (threadIdx.x < PERK) { sb1[threadIdx.x] = b1[threadIdx.x]; sw2[threadIdx.x] = w2[threadIdx.x]; }
    __syncthreads();
    int gid = blockIdx.x * blockDim.x + threadIdx.x;   // 8192 threads
    int b = gid >> 10, w = gid & 1023;
    float hid[PERK];
    #pragma unroll
    for (int j = 0; j < PERK; ++j) hid[j] = sb1[j];
    const float* pp = pooled + (size_t)b * CC * NWIN + w;
    for (int c = 0; c < CC; ++c) {
        float pv = pp[(size_t)c * NWIN];
        #pragma unroll
        for (int j = 0; j < PERK; ++j) hid[j] += pv * sw1[j * CC + c];
    }
    float lg = b2[0];
    #pragma unroll
    for (int j = 0; j < PERK; ++j) {
        float hv = hid[j];
        float g = 0.5f * hv * (1.0f + erff(hv * 0.7071067811865476f));
        lg += g * sw2[j];
    }
    logits[gid] = lg;
}

// -------- K3: softmax over 1024 windows + stable descending rank --------
__global__ void k_rank(const float* __restrict__ logits, float* __restrict__ probs,
                       float* __restrict__ rw, int* __restrict__ rank, int* __restrict__ sel) {
    __shared__ float sp[NWIN];
    __shared__ float red[NWIN];
    int b = blockIdx.x, t = threadIdx.x;
    float lg = logits[b * NWIN + t];
    red[t] = lg; __syncthreads();
    for (int o = 512; o > 0; o >>= 1) { if (t < o) red[t] = fmaxf(red[t], red[t + o]); __syncthreads(); }
    float mx = red[0]; __syncthreads();
    float e = expf(lg - mx);
    red[t] = e; __syncthreads();
    for (int o = 512; o > 0; o >>= 1) { if (t < o) red[t] += red[t + o]; __syncthreads(); }
    float p = e / red[0];
    sp[t] = p;
    probs[b * NWIN + t] = p;
    __syncthreads();
    int r = 0;
    for (int j = 0; j < NWIN; ++j) {
        float pj = sp[j];
        r += (int)((pj > p) || (pj == p && j < t));   // stable descending: jax.lax.top_k
    }
    rank[b * NWIN + t] = r;
    if (r < TOPK) { sel[b * TOPK + r] = t; rw[b * TOPK + r] = p; }
}

// scan-position l -> grid (a=row,b2=col) and pixel (wi,wj), per direction k
__device__ __forceinline__ void decode_l(int k, int l, int& a, int& b2, int& wi, int& wj) {
    int u = (k >= 2) ? (LL - 1 - l) : l;
    int q = u / 49, pix = u - q * 49;
    if ((k & 1) == 0) { a = q >> 4; b2 = q & 15; wi = pix / 7; wj = pix - wi * 7; }
    else             { b2 = q >> 4; a = q & 15; wj = pix / 7; wi = pix - wj * 7; }
}

// -------- K4: phase-1 chunk scan: per-chunk (P = prod a, S = local state) --------
__global__ __launch_bounds__(384) void k_phase1(
        const float* __restrict__ x, const float* __restrict__ xpw,
        const float* __restrict__ dtw, const float* __restrict__ dtb,
        const float* __restrict__ alogs, const int* __restrict__ sel,
        float* __restrict__ carrP, float* __restrict__ carrS) {
    __shared__ float sxs[PERK][LC];
    __shared__ float sdelta[PERK][LC];
    __shared__ float sB[DST][LC];
    __shared__ float sdts[DTR][LC];
    __shared__ float sxp[22 * PERK];
    __shared__ float sdtw[PERK * DTR];
    __shared__ float sbias[PERK];
    int blk = blockIdx.x;               // bk*TCH + t
    int t = blk % TCH; int bk = blk / TCH; int k = bk & 3; int b = bk >> 2;
    int tid = threadIdx.x;
    for (int i = tid; i < 22 * PERK; i += 384) sxp[i] = xpw[(k * 38) * PERK + i];
    for (int i = tid; i < PERK * DTR; i += 384) sdtw[i] = dtw[k * PERK * DTR + i];
    if (tid < PERK) sbias[tid] = dtb[k * PERK + tid];
    int l0 = t * LC;
    // gather xs
    for (int idx = tid; idx < PERK * LC; idx += 384) {
        int d = idx / LC, j = idx - d * LC;
        int a, b2, wi, wj; decode_l(k, l0 + j, a, b2, wi, wj);
        int wsel = sel[b * TOPK + a * 16 + b2];
        int gi = (wsel >> 5) * 7 + wi, gj = (wsel & 31) * 7 + wj;
        sxs[d][j] = x[(((size_t)b * CC + (4 * d + k)) * HH + gi) * HH + gj];
    }
    __syncthreads();
    // x_proj rows 0..21 (dts, B)
    for (int idx = tid; idx < 22 * LC; idx += 384) {
        int row = idx / LC, j = idx - row * LC;
        float acc = 0.f;
        #pragma unroll
        for (int d = 0; d < PERK; ++d) acc += sxp[row * PERK + d] * sxs[d][j];
        if (row < DTR) sdts[row][j] = acc; else sB[row - DTR][j] = acc;
    }
    __syncthreads();
    // delta = softplus(dt_proj(dts) + bias)
    for (int idx = tid; idx < PERK * LC; idx += 384) {
        int d = idx / LC, j = idx - d * LC;
        float acc = sbias[d];
        #pragma unroll
        for (int r = 0; r < DTR; ++r) acc += sdtw[d * DTR + r] * sdts[r][j];
        sdelta[d][j] = fmaxf(acc, 0.f) + log1pf(expf(-fabsf(acc)));
    }
    __syncthreads();
    int d = tid >> 4, s = tid & 15;
    float A = -expf(alogs[(k * PERK + d) * DST + s]);
    float P = 1.f, S = 0.f;
    for (int j = 0; j < LC; ++j) {
        float dl = sdelta[d][j];
        float aa = expf(dl * A);
        float du = dl * sxs[d][j];
        S = aa * S + du * sB[s][j];
        P *= aa;
    }
    size_t cidx = (size_t)blk * 384 + tid;
    carrP[cidx] = P; carrS[cidx] = S;
}

// -------- K5: carry scan across chunks --------
__global__ void k_carry(const float* __restrict__ carrP, const float* __restrict__ carrS,
                        float* __restrict__ hin) {
    int gid = blockIdx.x * blockDim.x + threadIdx.x;   // 12288
    int bk = gid / 384, ds = gid - bk * 384;
    float Hv = 0.f;
    for (int t = 0; t < TCH; ++t) {
        size_t idx = ((size_t)bk * TCH + t) * 384 + ds;
        hin[idx] = Hv;
        Hv = carrP[idx] * Hv + carrS[idx];
    }
}

// -------- K6: base output: x*(1+p) unselected, x selected --------
__global__ __launch_bounds__(64) void k_base(const float* __restrict__ x,
        const float* __restrict__ probs, const int* __restrict__ rank,
        float* __restrict__ out) {
    int wr = blockIdx.x % NHW; int bc = blockIdx.x / NHW;
    int b = bc / CC;
    __shared__ float buf[7 * HH];
    __shared__ float fmul[NHW];
    int tid = threadIdx.x;
    const float* xp = x + ((size_t)bc * HH + wr * 7) * HH;
    for (int i = tid; i < 7 * HH; i += 64) buf[i] = xp[i];
    if (tid < NHW) {
        int w = wr * NHW + tid;
        fmul[tid] = (rank[b * NWIN + w] < TOPK) ? 1.0f : (1.0f + probs[b * NWIN + w]);
    }
    __syncthreads();
    int c = bc - b * CC;
    for (int idx = tid; idx < NHW * 49; idx += 64) {
        int wc = idx / 49, r = idx - wc * 49;
        int ri = r / 7, rj = r - ri * 7;
        float v = buf[ri * HH + wc * 7 + rj];
        int w = wr * NHW + wc;
        out[(((size_t)b * NWIN + w) * CC + c) * 49 + r] = v * fmul[wc];
    }
}

// -------- K7: phase-3 scan with carry-in + y + inverse permutation + scatter-add --------
__global__ __launch_bounds__(384) void k_scan(
        const float* __restrict__ x, const float* __restrict__ xpw,
        const float* __restrict__ dtw, const float* __restrict__ dtb,
        const float* __restrict__ alogs, const float* __restrict__ dsv,
        const int* __restrict__ sel, const float* __restrict__ rw,
        const float* __restrict__ hin, float* __restrict__ out) {
    __shared__ float sxs[PERK][LC];
    __shared__ float sdelta[PERK][LC];
    __shared__ float sB[DST][LC];
    __shared__ float sC[DST][LC];
    __shared__ float sy[PERK][LC];       // rows 0..5 double as dts scratch
    __shared__ float sxp[38 * PERK];
    __shared__ float sdtw[PERK * DTR];
    __shared__ float sbias[PERK];
    __shared__ int   obase[LC];
    __shared__ float srwj[LC];
    int blk = blockIdx.x;
    int t = blk % TCH; int bk = blk / TCH; int k = bk & 3; int b = bk >> 2;
    int tid = threadIdx.x;
    for (int i = tid; i < 38 * PERK; i += 384) sxp[i] = xpw[k * 38 * PERK + i];
    for (int i = tid; i < PERK * DTR; i += 384) sdtw[i] = dtw[k * PERK * DTR + i];
    if (tid < PERK) sbias[tid] = dtb[k * PERK + tid];
    int l0 = t * LC;
    if (tid < LC) {
        int a, b2, wi, wj; decode_l(k, l0 + tid, a, b2, wi, wj);
        int lp = ((a * 7 + wi) * 16 + b2) * 7 + wj;          // local_reverse target
        int qo = lp / 49, ro = lp - qo * 49;
        int wsel = sel[b * TOPK + qo];
        obase[tid] = ((b * NWIN + wsel) * CC + k * PERK) * 49 + ro;
        srwj[tid] = rw[b * TOPK + qo];
    }
    for (int idx = tid; idx < PERK * LC; idx += 384) {
        int d = idx / LC, j = idx - d * LC;
        int a, b2, wi, wj; decode_l(k, l0 + j, a, b2, wi, wj);
        int wsel = sel[b * TOPK + a * 16 + b2];
        int gi = (wsel >> 5) * 7 + wi, gj = (wsel & 31) * 7 + wj;
        sxs[d][j] = x[(((size_t)b * CC + (4 * d + k)) * HH + gi) * HH + gj];
    }
    __syncthreads();
    for (int idx = tid; idx < 38 * LC; idx += 384) {
        int row = idx / LC, j = idx - row * LC;
        float acc = 0.f;
        #pragma unroll
        for (int d = 0; d < PERK; ++d) acc += sxp[row * PERK + d] * sxs[d][j];
        if (row < DTR) sy[row][j] = acc;
        else if (row < DTR + DST) sB[row - DTR][j] = acc;
        else sC[row - DTR - DST][j] = acc;
    }
    __syncthreads();
    for (int idx = tid; idx < PERK * LC; idx += 384) {
        int d = idx / LC, j = idx - d * LC;
        float acc = sbias[d];
        #pragma unroll
        for (int r = 0; r < DTR; ++r) acc += sdtw[d * DTR + r] * sy[r][j];
        sdelta[d][j] = fmaxf(acc, 0.f) + log1pf(expf(-fabsf(acc)));
    }
    __syncthreads();
    int d = tid >> 4, s = tid & 15;
    float A = -expf(alogs[(k * PERK + d) * DST + s]);
    float Dsr = dsv[k * PERK + d];
    size_t cidx = (size_t)blk * 384 + tid;
    float h = hin[cidx];
    for (int j = 0; j < LC; ++j) {
        float dl = sdelta[d][j];
        float aa = expf(dl * A);
        float du = dl * sxs[d][j];
        h = aa * h + du * sB[s][j];
        float part = h * sC[s][j];
        part += __shfl_xor(part, 1, 16);
        part += __shfl_xor(part, 2, 16);
        part += __shfl_xor(part, 4, 16);
        part += __shfl_xor(part, 8, 16);
        if (s == 0) sy[d][j] = part + sxs[d][j] * Dsr;
    }
    __syncthreads();
    for (int idx = tid; idx < PERK * LC; idx += 384) {
        int d2 = idx / LC, j = idx - d2 * LC;
        int addr = obase[j] + d2 * 49;
        out[addr] += sy[d2][j] * srwj[j];
    }
}

extern "C" void kernel_launch(void* const* d_in, const int* in_sizes, int n_in,
                              void* d_out, int out_size, void* d_ws, size_t ws_size,
                              hipStream_t stream) {
    const float* x   = (const float*)d_in[0];
    const float* w1  = (const float*)d_in[1];
    const float* b1  = (const float*)d_in[2];
    const float* w2  = (const float*)d_in[3];
    const float* b2  = (const float*)d_in[4];
    const float* xpw = (const float*)d_in[5];
    const float* dtw = (const float*)d_in[6];
    const float* dtb = (const float*)d_in[7];
    const float* alg = (const float*)d_in[8];
    const float* dsv = (const float*)d_in[9];
    float* out = (float*)d_out;
    float* ws  = (float*)d_ws;

    float* pooled = ws + OFF_POOL;
    float* logits = ws + OFF_LOG;
    float* probs  = ws + OFF_PROB;
    float* rwv    = ws + OFF_RW;
    int*   rank   = (int*)(ws + OFF_RANK);
    int*   sel    = (int*)(ws + OFF_SEL);
    float* cP  = ws + OFF_CP;
    float* cS  = ws + OFF_CS;
    float* hin = ws + OFF_HIN;

    k_pool  <<<BBATCH * CC, 256, 0, stream>>>(x, pooled);
    k_router<<<BBATCH * NWIN / 256, 256, 0, stream>>>(pooled, w1, b1, w2, b2, logits);
    k_rank  <<<BBATCH, 1024, 0, stream>>>(logits, probs, rwv, rank, sel);
    k_phase1<<<NBK * TCH, 384, 0, stream>>>(x, xpw, dtw, dtb, alg, sel, cP, cS);
    k_carry <<<48, 256, 0, stream>>>(cP, cS, hin);
    k_base  <<<BBATCH * CC * NHW, 64, 0, stream>>>(x, probs, rank, out);
    k_scan  <<<NBK * TCH, 384, 0, stream>>>(x, xpw, dtw, dtb, alg, dsv, sel, rwv, hin, out);
}

// Round 2
// 529.517 us; speedup vs baseline: 1.2387x; 1.2387x over previous
//
#include <hip/hip_runtime.h>
#include <math.h>

// Problem constants
#define BBATCH 8
#define CC 96
#define HH 224
#define NHW 32            // 224/7 windows per side
#define NWIN 1024
#define TOPK 256
#define PERK 24
#define DST 16
#define DTR 6
#define LL 12544          // 256*49
#define LC 98             // chunk length (2 windows)
#define LCP 100           // padded row length (16B-aligned rows, zero pad cols 98,99)
#define NG 25             // float4 groups per row
#define TCH 128           // chunks: 128*98 = 12544
#define NBK 32            // B*4 directions

// workspace offsets (floats)
#define OFF_POOL 0
#define OFF_LOG  786432
#define OFF_PROB 794624
#define OFF_RW   802816
#define OFF_RANK 804864
#define OFF_SEL  813056
#define OFF_CP   815104
#define OFF_CS   2387968
#define OFF_HIN  3960832

// DPP row_ror:N add — 16-lane full-sum reduction on the VALU pipe (not DS)
#define ROR_ADD(v, CTRL) \
    v += __int_as_float(__builtin_amdgcn_update_dpp(0, __float_as_int(v), CTRL, 0xf, 0xf, true))

// -------- K1: window pooling: pooledT[b][c][w] --------
__global__ void k_pool(const float* __restrict__ x, float* __restrict__ pooled) {
    int bc = blockIdx.x;                 // b*96+c
    const float* xp = x + (size_t)bc * HH * HH;
    float* pp = pooled + (size_t)bc * NWIN;
    for (int w = threadIdx.x; w < NWIN; w += blockDim.x) {
        int wr = w >> 5, wc = w & 31;
        const float* base = xp + (wr * 7) * HH + wc * 7;
        float s = 0.f;
        #pragma unroll
        for (int i = 0; i < 7; ++i) {
            #pragma unroll
            for (int j = 0; j < 7; ++j) s += base[i * HH + j];
        }
        pp[w] = s * (1.0f / 49.0f);
    }
}

// -------- K2: router MLP -> logits --------
__global__ void k_router(const float* __restrict__ pooled,
                         const float* __restrict__ w1, const float* __restrict__ b1,
                         const float* __restrict__ w2, const float* __restrict__ b2,
                         float* __restrict__ logits) {
    __shared__ float sw1[PERK * CC];
    __shared__ float sb1[PERK];
    __shared__ float sw2[PERK];
    for (int i = threadIdx.x; i < PERK * CC; i += blockDim.x) sw1[i] = w1[i];
    if (threadIdx.x < PERK) { sb1[threadIdx.x] = b1[threadIdx.x]; sw2[threadIdx.x] = w2[threadIdx.x]; }
    __syncthreads();
    int gid = blockIdx.x * blockDim.x + threadIdx.x;   // 8192 threads
    int b = gid >> 10, w = gid & 1023;
    float hid[PERK];
    #pragma unroll
    for (int j = 0; j < PERK; ++j) hid[j] = sb1[j];
    const float* pp = pooled + (size_t)b * CC * NWIN + w;
    for (int c = 0; c < CC; ++c) {
        float pv = pp[(size_t)c * NWIN];
        #pragma unroll
        for (int j = 0; j < PERK; ++j) hid[j] += pv * sw1[j * CC + c];
    }
    float lg = b2[0];
    #pragma unroll
    for (int j = 0; j < PERK; ++j) {
        float hv = hid[j];
        float g = 0.5f * hv * (1.0f + erff(hv * 0.7071067811865476f));
        lg += g * sw2[j];
    }
    logits[gid] = lg;
}

// -------- K3: softmax over 1024 windows + stable descending rank --------
__global__ void k_rank(const float* __restrict__ logits, float* __restrict__ probs,
                       float* __restrict__ rw, int* __restrict__ rank, int* __restrict__ sel) {
    __shared__ __attribute__((aligned(16))) float sp[NWIN];
    __shared__ float red[NWIN];
    int b = blockIdx.x, t = threadIdx.x;
    float lg = logits[b * NWIN + t];
    red[t] = lg; __syncthreads();
    for (int o = 512; o > 0; o >>= 1) { if (t < o) red[t] = fmaxf(red[t], red[t + o]); __syncthreads(); }
    float mx = red[0]; __syncthreads();
    float e = expf(lg - mx);
    red[t] = e; __syncthreads();
    for (int o = 512; o > 0; o >>= 1) { if (t < o) red[t] += red[t + o]; __syncthreads(); }
    float p = e / red[0];
    sp[t] = p;
    probs[b * NWIN + t] = p;
    __syncthreads();
    int r = 0;
    for (int j = 0; j < NWIN; j += 4) {
        float4 pj = *(const float4*)&sp[j];
        r += (int)((pj.x > p) || (pj.x == p && (j + 0) < t));
        r += (int)((pj.y > p) || (pj.y == p && (j + 1) < t));
        r += (int)((pj.z > p) || (pj.z == p && (j + 2) < t));
        r += (int)((pj.w > p) || (pj.w == p && (j + 3) < t));
    }
    rank[b * NWIN + t] = r;
    if (r < TOPK) { sel[b * TOPK + r] = t; rw[b * TOPK + r] = p; }
}

// scan-position l -> grid (a=row,b2=col) and pixel (wi,wj), per direction k
__device__ __forceinline__ void decode_l(int k, int l, int& a, int& b2, int& wi, int& wj) {
    int u = (k >= 2) ? (LL - 1 - l) : l;
    int q = u / 49, pix = u - q * 49;
    if ((k & 1) == 0) { a = q >> 4; b2 = q & 15; wi = pix / 7; wj = pix - wi * 7; }
    else             { b2 = q >> 4; a = q & 15; wj = pix / 7; wi = pix - wj * 7; }
}

// -------- K4: phase-1 chunk scan: per-chunk (P = prod a, S = local state) --------
__global__ __launch_bounds__(384) void k_phase1(
        const float* __restrict__ x, const float* __restrict__ xpw,
        const float* __restrict__ dtw, const float* __restrict__ dtb,
        const float* __restrict__ alogs, const int* __restrict__ sel,
        float* __restrict__ carrP, float* __restrict__ carrS) {
    __shared__ __attribute__((aligned(16))) float sxs[PERK][LCP];
    __shared__ __attribute__((aligned(16))) float sdelta[PERK][LCP];
    __shared__ __attribute__((aligned(16))) float sB[DST][LCP];
    __shared__ __attribute__((aligned(16))) float sdts[DTR][LCP];
    __shared__ float sxp[22 * PERK];
    __shared__ float sdtw[PERK * DTR];
    __shared__ float sbias[PERK];
    int blk = blockIdx.x;               // bk*TCH + t
    int t = blk % TCH; int bk = blk / TCH; int k = bk & 3; int b = bk >> 2;
    int tid = threadIdx.x;
    for (int i = tid; i < 22 * PERK; i += 384) sxp[i] = xpw[(k * 38) * PERK + i];
    for (int i = tid; i < PERK * DTR; i += 384) sdtw[i] = dtw[k * PERK * DTR + i];
    if (tid < PERK) sbias[tid] = dtb[k * PERK + tid];
    // zero pad columns (never overwritten afterwards)
    if (tid < 2 * PERK) { int d = tid >> 1, j = 98 + (tid & 1); sxs[d][j] = 0.f; sdelta[d][j] = 0.f; }
    else if (tid < 2 * PERK + 2 * DST) { int i = tid - 2 * PERK; sB[i >> 1][98 + (i & 1)] = 0.f; }
    int l0 = t * LC;
    // gather xs (columns 0..97 only)
    for (int idx = tid; idx < PERK * LC; idx += 384) {
        int d = idx / LC, j = idx - d * LC;
        int a, b2, wi, wj; decode_l(k, l0 + j, a, b2, wi, wj);
        int wsel = sel[b * TOPK + a * 16 + b2];
        int gi = (wsel >> 5) * 7 + wi, gj = (wsel & 31) * 7 + wj;
        sxs[d][j] = x[(((size_t)b * CC + (4 * d + k)) * HH + gi) * HH + gj];
    }
    __syncthreads();
    // x_proj rows 0..21 (dts, B) — 4 outputs per task, guarded tail store
    for (int idx = tid; idx < 22 * NG; idx += 384) {
        int row = idx / NG, g = idx - row * NG; int j = g * 4;
        float ax = 0.f, ay = 0.f, az = 0.f, aw = 0.f;
        #pragma unroll
        for (int d = 0; d < PERK; ++d) {
            float w = sxp[row * PERK + d];
            float4 v = *(const float4*)&sxs[d][j];
            ax += w * v.x; ay += w * v.y; az += w * v.z; aw += w * v.w;
        }
        float* dst = (row < DTR) ? &sdts[row][j] : &sB[row - DTR][j];
        if (j < 96) { float4 o = {ax, ay, az, aw}; *(float4*)dst = o; }
        else { dst[0] = ax; dst[1] = ay; }
    }
    __syncthreads();
    // delta = softplus(dt_proj(dts) + bias)
    for (int idx = tid; idx < PERK * NG; idx += 384) {
        int d = idx / NG, g = idx - d * NG; int j = g * 4;
        float ax = sbias[d], ay = ax, az = ax, aw = ax;
        #pragma unroll
        for (int r = 0; r < DTR; ++r) {
            float w = sdtw[d * DTR + r];
            float4 v = *(const float4*)&sdts[r][j];
            ax += w * v.x; ay += w * v.y; az += w * v.z; aw += w * v.w;
        }
        ax = fmaxf(ax, 0.f) + log1pf(__expf(-fabsf(ax)));
        ay = fmaxf(ay, 0.f) + log1pf(__expf(-fabsf(ay)));
        az = fmaxf(az, 0.f) + log1pf(__expf(-fabsf(az)));
        aw = fmaxf(aw, 0.f) + log1pf(__expf(-fabsf(aw)));
        if (j < 96) { float4 o = {ax, ay, az, aw}; *(float4*)&sdelta[d][j] = o; }
        else { sdelta[d][j] = ax; sdelta[d][j + 1] = ay; }
    }
    __syncthreads();
    int d = tid >> 4, s = tid & 15;
    float A = -__expf(alogs[(k * PERK + d) * DST + s]);
    float P = 1.f, S = 0.f;
    for (int g = 0; g < NG; ++g) {
        int j = g * 4;
        float4 dl4 = *(const float4*)&sdelta[d][j];   // pads = 0
        float4 xs4 = *(const float4*)&sxs[d][j];      // pads = 0
        float4 B4  = *(const float4*)&sB[s][j];       // pads = 0
        float aa;
        aa = __expf(dl4.x * A); S = aa * S + (dl4.x * xs4.x) * B4.x; P *= aa;
        aa = __expf(dl4.y * A); S = aa * S + (dl4.y * xs4.y) * B4.y; P *= aa;
        aa = __expf(dl4.z * A); S = aa * S + (dl4.z * xs4.z) * B4.z; P *= aa;
        aa = __expf(dl4.w * A); S = aa * S + (dl4.w * xs4.w) * B4.w; P *= aa;
    }
    size_t cidx = (size_t)blk * 384 + tid;
    carrP[cidx] = P; carrS[cidx] = S;
}

// -------- K5: carry scan across chunks --------
__global__ void k_carry(const float* __restrict__ carrP, const float* __restrict__ carrS,
                        float* __restrict__ hin) {
    int gid = blockIdx.x * blockDim.x + threadIdx.x;   // 12288
    int bk = gid / 384, ds = gid - bk * 384;
    float Hv = 0.f;
    for (int t = 0; t < TCH; ++t) {
        size_t idx = ((size_t)bk * TCH + t) * 384 + ds;
        hin[idx] = Hv;
        Hv = carrP[idx] * Hv + carrS[idx];
    }
}

// -------- K6: base output: x*(1+p) unselected, x selected --------
__global__ __launch_bounds__(64) void k_base(const float* __restrict__ x,
        const float* __restrict__ probs, const int* __restrict__ rank,
        float* __restrict__ out) {
    int wr = blockIdx.x % NHW; int bc = blockIdx.x / NHW;
    int b = bc / CC;
    __shared__ float buf[7 * HH];
    __shared__ float fmul[NHW];
    int tid = threadIdx.x;
    const float* xp = x + ((size_t)bc * HH + wr * 7) * HH;
    for (int i = tid; i < 7 * HH; i += 64) buf[i] = xp[i];
    if (tid < NHW) {
        int w = wr * NHW + tid;
        fmul[tid] = (rank[b * NWIN + w] < TOPK) ? 1.0f : (1.0f + probs[b * NWIN + w]);
    }
    __syncthreads();
    int c = bc - b * CC;
    for (int idx = tid; idx < NHW * 49; idx += 64) {
        int wc = idx / 49, r = idx - wc * 49;
        int ri = r / 7, rj = r - ri * 7;
        float v = buf[ri * HH + wc * 7 + rj];
        int w = wr * NHW + wc;
        out[(((size_t)b * NWIN + w) * CC + c) * 49 + r] = v * fmul[wc];
    }
}

// -------- K7: phase-3 scan with carry-in + y + inverse permutation + scatter-add --------
__global__ __launch_bounds__(384) void k_scan(
        const float* __restrict__ x, const float* __restrict__ xpw,
        const float* __restrict__ dtw, const float* __restrict__ dtb,
        const float* __restrict__ alogs, const float* __restrict__ dsv,
        const int* __restrict__ sel, const float* __restrict__ rw,
        const float* __restrict__ hin, float* __restrict__ out) {
    __shared__ __attribute__((aligned(16))) float sxs[PERK][LCP];
    __shared__ __attribute__((aligned(16))) float sdelta[PERK][LCP];
    __shared__ __attribute__((aligned(16))) float sB[DST][LCP];
    __shared__ __attribute__((aligned(16))) float sC[DST][LCP];
    __shared__ __attribute__((aligned(16))) float sy[PERK][LCP];  // rows 0..5 double as dts scratch
    __shared__ float sxp[38 * PERK];
    __shared__ float sdtw[PERK * DTR];
    __shared__ float sbias[PERK];
    __shared__ int   obase[LC];
    __shared__ float srwj[LC];
    int blk = blockIdx.x;
    int t = blk % TCH; int bk = blk / TCH; int k = bk & 3; int b = bk >> 2;
    int tid = threadIdx.x;
    for (int i = tid; i < 38 * PERK; i += 384) sxp[i] = xpw[k * 38 * PERK + i];
    for (int i = tid; i < PERK * DTR; i += 384) sdtw[i] = dtw[k * PERK * DTR + i];
    if (tid < PERK) sbias[tid] = dtb[k * PERK + tid];
    // zero pad columns
    if (tid < 2 * PERK) { int d = tid >> 1, j = 98 + (tid & 1); sxs[d][j] = 0.f; sdelta[d][j] = 0.f; }
    else if (tid < 2 * PERK + 2 * DST) { int i = tid - 2 * PERK; int s2 = i >> 1, j = 98 + (i & 1); sB[s2][j] = 0.f; sC[s2][j] = 0.f; }
    int l0 = t * LC;
    if (tid < LC) {
        int a, b2, wi, wj; decode_l(k, l0 + tid, a, b2, wi, wj);
        int lp = ((a * 7 + wi) * 16 + b2) * 7 + wj;          // local_reverse target
        int qo = lp / 49, ro = lp - qo * 49;
        int wsel = sel[b * TOPK + qo];
        obase[tid] = ((b * NWIN + wsel) * CC + k * PERK) * 49 + ro;
        srwj[tid] = rw[b * TOPK + qo];
    }
    for (int idx = tid; idx < PERK * LC; idx += 384) {
        int d = idx / LC, j = idx - d * LC;
        int a, b2, wi, wj; decode_l(k, l0 + j, a, b2, wi, wj);
        int wsel = sel[b * TOPK + a * 16 + b2];
        int gi = (wsel >> 5) * 7 + wi, gj = (wsel & 31) * 7 + wj;
        sxs[d][j] = x[(((size_t)b * CC + (4 * d + k)) * HH + gi) * HH + gj];
    }
    __syncthreads();
    // x_proj rows 0..37 (dts, B, C)
    for (int idx = tid; idx < 38 * NG; idx += 384) {
        int row = idx / NG, g = idx - row * NG; int j = g * 4;
        float ax = 0.f, ay = 0.f, az = 0.f, aw = 0.f;
        #pragma unroll
        for (int d = 0; d < PERK; ++d) {
            float w = sxp[row * PERK + d];
            float4 v = *(const float4*)&sxs[d][j];
            ax += w * v.x; ay += w * v.y; az += w * v.z; aw += w * v.w;
        }
        float* dst;
        if (row < DTR) dst = &sy[row][j];
        else if (row < DTR + DST) dst = &sB[row - DTR][j];
        else dst = &sC[row - DTR - DST][j];
        if (j < 96) { float4 o = {ax, ay, az, aw}; *(float4*)dst = o; }
        else { dst[0] = ax; dst[1] = ay; }
    }
    __syncthreads();
    for (int idx = tid; idx < PERK * NG; idx += 384) {
        int d = idx / NG, g = idx - d * NG; int j = g * 4;
        float ax = sbias[d], ay = ax, az = ax, aw = ax;
        #pragma unroll
        for (int r = 0; r < DTR; ++r) {
            float w = sdtw[d * DTR + r];
            float4 v = *(const float4*)&sy[r][j];
            ax += w * v.x; ay += w * v.y; az += w * v.z; aw += w * v.w;
        }
        ax = fmaxf(ax, 0.f) + log1pf(__expf(-fabsf(ax)));
        ay = fmaxf(ay, 0.f) + log1pf(__expf(-fabsf(ay)));
        az = fmaxf(az, 0.f) + log1pf(__expf(-fabsf(az)));
        aw = fmaxf(aw, 0.f) + log1pf(__expf(-fabsf(aw)));
        if (j < 96) { float4 o = {ax, ay, az, aw}; *(float4*)&sdelta[d][j] = o; }
        else { sdelta[d][j] = ax; sdelta[d][j + 1] = ay; }
    }
    __syncthreads();
    int d = tid >> 4, s = tid & 15;
    float A = -__expf(alogs[(k * PERK + d) * DST + s]);
    float Dsr = dsv[k * PERK + d];
    size_t cidx = (size_t)blk * 384 + tid;
    float h = hin[cidx];
    for (int g = 0; g < NG; ++g) {
        int j = g * 4;
        float4 dl4 = *(const float4*)&sdelta[d][j];
        float4 xs4 = *(const float4*)&sxs[d][j];
        float4 B4  = *(const float4*)&sB[s][j];
        float4 C4  = *(const float4*)&sC[s][j];
        float aa, part;
        aa = __expf(dl4.x * A); h = aa * h + (dl4.x * xs4.x) * B4.x;
        part = h * C4.x;
        ROR_ADD(part, 0x121); ROR_ADD(part, 0x122); ROR_ADD(part, 0x124); ROR_ADD(part, 0x128);
        if (s == 0) sy[d][j] = part + xs4.x * Dsr;
        aa = __expf(dl4.y * A); h = aa * h + (dl4.y * xs4.y) * B4.y;
        part = h * C4.y;
        ROR_ADD(part, 0x121); ROR_ADD(part, 0x122); ROR_ADD(part, 0x124); ROR_ADD(part, 0x128);
        if (s == 0) sy[d][j + 1] = part + xs4.y * Dsr;
        aa = __expf(dl4.z * A); h = aa * h + (dl4.z * xs4.z) * B4.z;
        part = h * C4.z;
        ROR_ADD(part, 0x121); ROR_ADD(part, 0x122); ROR_ADD(part, 0x124); ROR_ADD(part, 0x128);
        if (s == 0) sy[d][j + 2] = part + xs4.z * Dsr;
        aa = __expf(dl4.w * A); h = aa * h + (dl4.w * xs4.w) * B4.w;
        part = h * C4.w;
        ROR_ADD(part, 0x121); ROR_ADD(part, 0x122); ROR_ADD(part, 0x124); ROR_ADD(part, 0x128);
        if (s == 0) sy[d][j + 3] = part + xs4.w * Dsr;
    }
    __syncthreads();
    for (int idx = tid; idx < PERK * LC; idx += 384) {
        int d2 = idx / LC, j = idx - d2 * LC;
        int addr = obase[j] + d2 * 49;
        out[addr] += sy[d2][j] * srwj[j];
    }
}

extern "C" void kernel_launch(void* const* d_in, const int* in_sizes, int n_in,
                              void* d_out, int out_size, void* d_ws, size_t ws_size,
                              hipStream_t stream) {
    const float* x   = (const float*)d_in[0];
    const float* w1  = (const float*)d_in[1];
    const float* b1  = (const float*)d_in[2];
    const float* w2  = (const float*)d_in[3];
    const float* b2  = (const float*)d_in[4];
    const float* xpw = (const float*)d_in[5];
    const float* dtw = (const float*)d_in[6];
    const float* dtb = (const float*)d_in[7];
    const float* alg = (const float*)d_in[8];
    const float* dsv = (const float*)d_in[9];
    float* out = (float*)d_out;
    float* ws  = (float*)d_ws;

    float* pooled = ws + OFF_POOL;
    float* logits = ws + OFF_LOG;
    float* probs  = ws + OFF_PROB;
    float* rwv    = ws + OFF_RW;
    int*   rank   = (int*)(ws + OFF_RANK);
    int*   sel    = (int*)(ws + OFF_SEL);
    float* cP  = ws + OFF_CP;
    float* cS  = ws + OFF_CS;
    float* hin = ws + OFF_HIN;

    k_pool  <<<BBATCH * CC, 256, 0, stream>>>(x, pooled);
    k_router<<<BBATCH * NWIN / 256, 256, 0, stream>>>(pooled, w1, b1, w2, b2, logits);
    k_rank  <<<BBATCH, 1024, 0, stream>>>(logits, probs, rwv, rank, sel);
    k_phase1<<<NBK * TCH, 384, 0, stream>>>(x, xpw, dtw, dtb, alg, sel, cP, cS);
    k_carry <<<48, 256, 0, stream>>>(cP, cS, hin);
    k_base  <<<BBATCH * CC * NHW, 64, 0, stream>>>(x, probs, rank, out);
    k_scan  <<<NBK * TCH, 384, 0, stream>>>(x, xpw, dtw, dtb, alg, dsv, sel, rwv, hin, out);
}